// Round 9
// baseline (2856.085 us; speedup 1.0000x reference)
//
#include <hip/hip_runtime.h>

typedef __attribute__((ext_vector_type(8))) _Float16 half8;
typedef __attribute__((ext_vector_type(4))) _Float16 half4v;
typedef __attribute__((ext_vector_type(4))) float f32x4;

// ---------------------------------------------------------------- utilities
__device__ __forceinline__ void gload16(const void* g, void* l) {
  __builtin_amdgcn_global_load_lds((__attribute__((address_space(1))) void*)(g),
                                   (__attribute__((address_space(3))) void*)(l), 16, 0, 0);
}

// ---------------------------------------------------------------- embed + PE (ILP-vectorized)
__global__ __launch_bounds__(256) void embed_kernel(
    const float* __restrict__ obs, const float* __restrict__ act,
    const float* __restrict__ W_obs, const float* __restrict__ b_obs,
    const float* __restrict__ W_act, const float* __restrict__ b_act,
    float* __restrict__ e) {
  const int row = blockIdx.x;            // b*1024 + t
  const int b = row >> 10, t = row & 1023;
  const int pos = t >> 1;
  const bool is_act = t & 1;
  __shared__ float in_row[64];
  const int tid = threadIdx.x;
  if (!is_act) { if (tid < 64) in_row[tid] = obs[(size_t)(b * 512 + pos) * 64 + tid]; }
  else         { if (tid < 8)  in_row[tid] = act[(size_t)(b * 512 + pos) * 8 + tid]; }
  __syncthreads();
  const int d0 = tid * 4;                // each thread owns 4 consecutive d
  float a[4];
  if (!is_act) {
    #pragma unroll
    for (int j = 0; j < 4; ++j) a[j] = b_obs[d0 + j];
    #pragma unroll
    for (int c4 = 0; c4 < 16; ++c4) {
      const f32x4 iv = *(const f32x4*)&in_row[c4 * 4];
      #pragma unroll
      for (int j = 0; j < 4; ++j) {
        const f32x4 wv = *(const f32x4*)&W_obs[(size_t)(d0 + j) * 64 + c4 * 4];
        a[j] += iv[0] * wv[0] + iv[1] * wv[1] + iv[2] * wv[2] + iv[3] * wv[3];
      }
    }
  } else {
    #pragma unroll
    for (int j = 0; j < 4; ++j) a[j] = b_act[d0 + j];
    #pragma unroll
    for (int c4 = 0; c4 < 2; ++c4) {
      const f32x4 iv = *(const f32x4*)&in_row[c4 * 4];
      #pragma unroll
      for (int j = 0; j < 4; ++j) {
        const f32x4 wv = *(const f32x4*)&W_act[(size_t)(d0 + j) * 8 + c4 * 4];
        a[j] += iv[0] * wv[0] + iv[1] * wv[1] + iv[2] * wv[2] + iv[3] * wv[3];
      }
    }
  }
  #pragma unroll
  for (int jj = 0; jj < 2; ++jj) {
    const int j = (d0 >> 1) + jj;
    const float dv = expf((float)(2 * j) * (-9.210340371976184f / 1024.0f));
    const float ang = (float)pos * dv;
    a[jj * 2]     += sinf(ang);
    a[jj * 2 + 1] += cosf(ang);
  }
  f32x4 o; o[0] = a[0]; o[1] = a[1]; o[2] = a[2]; o[3] = a[3];
  *(f32x4*)&e[(size_t)row * 1024 + d0] = o;
}

// ---------------------------------------------------------------- layernorm -> f32(opt) + f16 hi/lo
template<bool RES, bool WF32>
__global__ __launch_bounds__(256) void ln_kernel(
    const float* __restrict__ in, const float* __restrict__ res,
    const float* __restrict__ g, const float* __restrict__ bta,
    float* __restrict__ of, _Float16* __restrict__ ohh, _Float16* __restrict__ ohl) {
  const int row = blockIdx.x;
  const size_t base = (size_t)row * 1024;
  const int tid = threadIdx.x;
  float v[4];
  {
    const f32x4 a = *(const f32x4*)&in[base + tid * 4];
    if (RES) {
      const f32x4 r = *(const f32x4*)&res[base + tid * 4];
      v[0] = a[0] + r[0]; v[1] = a[1] + r[1]; v[2] = a[2] + r[2]; v[3] = a[3] + r[3];
    } else {
      v[0] = a[0]; v[1] = a[1]; v[2] = a[2]; v[3] = a[3];
    }
  }
  float s = 0.f, sq = 0.f;
  #pragma unroll
  for (int c = 0; c < 4; ++c) { s += v[c]; sq += v[c] * v[c]; }
  #pragma unroll
  for (int off = 32; off; off >>= 1) { s += __shfl_down(s, off); sq += __shfl_down(sq, off); }
  __shared__ float rs[4], rq[4];
  const int wid = tid >> 6, lane = tid & 63;
  if (!lane) { rs[wid] = s; rq[wid] = sq; }
  __syncthreads();
  s = rs[0] + rs[1] + rs[2] + rs[3];
  sq = rq[0] + rq[1] + rq[2] + rq[3];
  const float mean = s * (1.f / 1024.f);
  const float var = sq * (1.f / 1024.f) - mean * mean;
  const float rstd = rsqrtf(var + 1e-5f);
  #pragma unroll
  for (int c = 0; c < 4; ++c) {
    const int d = tid * 4 + c;
    const float o = (v[c] - mean) * rstd * g[d] + bta[d];
    if (WF32) of[base + d] = o;
    const _Float16 hi = (_Float16)o;
    ohh[base + d] = hi;
    ohl[base + d] = (_Float16)(o - (float)hi);
  }
}

// ---------------------------------------------------------------- f32 -> f16 hi/lo split
__global__ __launch_bounds__(256) void f2h_split_kernel(const float* __restrict__ s,
                                                        _Float16* __restrict__ hi,
                                                        _Float16* __restrict__ lo, int n) {
  int i = (blockIdx.x * 256 + threadIdx.x) * 4;
  const int stride = gridDim.x * 256 * 4;
  for (; i < n; i += stride) {
    const f32x4 v = *(const f32x4*)&s[i];
    half4v h, l;
    #pragma unroll
    for (int c = 0; c < 4; ++c) {
      h[c] = (_Float16)v[c];
      l[c] = (_Float16)(v[c] - (float)h[c]);
    }
    *(half4v*)&hi[i] = h;
    *(half4v*)&lo[i] = l;
  }
}

// ---------------------------------------------------------------- split-f16 MFMA GEMM: C = A @ B^T
// A = Ah+Al (M x K), B = Bh+Bl (N x K), both row-major f16 pairs.
// C = Ah*Bh + Al*Bh + Ah*Bl  (f32-accurate; Al*Bl ~ 2^-44 dropped)
// K-loop: counted-vmcnt double buffer (T4) — prefetch stays in flight across barriers.
template<bool BIAS, bool GELU, bool WF32, bool WF16>
__global__ __launch_bounds__(256, 2) void gemm_bt(
    const _Float16* __restrict__ Ah, const _Float16* __restrict__ Al,
    const _Float16* __restrict__ Bh, const _Float16* __restrict__ Bl,
    const float* __restrict__ bias,
    float* __restrict__ Cf, _Float16* __restrict__ Chh, _Float16* __restrict__ Chl,
    const int M, const int N, const int K) {
  __shared__ _Float16 lds[2][4][4096];     // [buf][Ah/Al/Bh/Bl][128 rows x 32 k]
  const int tid = threadIdx.x;
  const int wid = tid >> 6, lane = tid & 63;
  const int wm = wid >> 1, wn = wid & 1;

  // bijective XCD-aware tile swizzle (T1): contiguous tile chunks per XCD.
  const int nwg = gridDim.x * gridDim.y;
  int flat = blockIdx.y * gridDim.x + blockIdx.x;
  flat = (flat & 7) * (nwg >> 3) + (flat >> 3);
  const int m0 = (flat / gridDim.x) * 128, n0 = (flat % gridDim.x) * 128;
  const int KT = K >> 5;

  f32x4 acc[4][4];
  #pragma unroll
  for (int i = 0; i < 4; ++i)
    #pragma unroll
    for (int j = 0; j < 4; ++j) acc[i][j] = f32x4{0.f, 0.f, 0.f, 0.f};

  // staging: each tile is 4096 halfs; 256 lanes x 16B covers 2048 halfs -> 2 chunks
  const int ho0 = wid * 512 + lane * 8;
  const int r0s = ho0 >> 5, kk0 = ho0 & 31;
  const int ho1 = (wid + 4) * 512 + lane * 8;
  const int r1s = ho1 >> 5, kk1 = ho1 & 31;

  auto stage = [&](int buf, int kt) {   // 8 gload16 per thread
    const int k0 = kt << 5;
    const size_t a0 = (size_t)(m0 + r0s) * K + k0 + kk0;
    const size_t a1 = (size_t)(m0 + r1s) * K + k0 + kk1;
    const size_t b0 = (size_t)(n0 + r0s) * K + k0 + kk0;
    const size_t b1 = (size_t)(n0 + r1s) * K + k0 + kk1;
    gload16(Ah + a0, &lds[buf][0][ho0]); gload16(Ah + a1, &lds[buf][0][ho1]);
    gload16(Al + a0, &lds[buf][1][ho0]); gload16(Al + a1, &lds[buf][1][ho1]);
    gload16(Bh + b0, &lds[buf][2][ho0]); gload16(Bh + b1, &lds[buf][2][ho1]);
    gload16(Bl + b0, &lds[buf][3][ho0]); gload16(Bl + b1, &lds[buf][3][ho1]);
  };

  stage(0, 0);
  int cur = 0;
  const int lr = lane & 15, lk = (lane >> 4) * 8;
  for (int kt = 0; kt < KT; ++kt) {
    if (kt + 1 < KT) {
      stage(cur ^ 1, kt + 1);                       // 8 newer loads in flight
      asm volatile("s_waitcnt vmcnt(8)" ::: "memory");  // wait only tile-kt's 8
    } else {
      asm volatile("s_waitcnt vmcnt(0)" ::: "memory");
    }
    __builtin_amdgcn_s_barrier();                   // buf[cur] valid for all waves
    const _Float16* lAh = &lds[cur][0][0];
    const _Float16* lAl = &lds[cur][1][0];
    const _Float16* lBh = &lds[cur][2][0];
    const _Float16* lBl = &lds[cur][3][0];
    half8 afh[4], afl[4], bfh[4], bfl[4];
    #pragma unroll
    for (int mi = 0; mi < 4; ++mi) {
      const int o = (wm * 64 + mi * 16 + lr) * 32 + lk;
      afh[mi] = *(const half8*)&lAh[o];
      afl[mi] = *(const half8*)&lAl[o];
    }
    #pragma unroll
    for (int ni = 0; ni < 4; ++ni) {
      const int o = (wn * 64 + ni * 16 + lr) * 32 + lk;
      bfh[ni] = *(const half8*)&lBh[o];
      bfl[ni] = *(const half8*)&lBl[o];
    }
    #pragma unroll
    for (int mi = 0; mi < 4; ++mi)
      #pragma unroll
      for (int ni = 0; ni < 4; ++ni) {
        acc[mi][ni] = __builtin_amdgcn_mfma_f32_16x16x32_f16(afh[mi], bfh[ni], acc[mi][ni], 0, 0, 0);
        acc[mi][ni] = __builtin_amdgcn_mfma_f32_16x16x32_f16(afl[mi], bfh[ni], acc[mi][ni], 0, 0, 0);
        acc[mi][ni] = __builtin_amdgcn_mfma_f32_16x16x32_f16(afh[mi], bfl[ni], acc[mi][ni], 0, 0, 0);
      }
    asm volatile("s_waitcnt lgkmcnt(0)" ::: "memory");  // all LDS reads of buf[cur] landed
    __builtin_amdgcn_s_barrier();                       // safe to overwrite next iter (no vmcnt drain!)
    cur ^= 1;
  }

  const int lq = lane >> 4;
  #pragma unroll
  for (int mi = 0; mi < 4; ++mi) {
    const int gr = m0 + wm * 64 + mi * 16 + lq * 4;
    #pragma unroll
    for (int ni = 0; ni < 4; ++ni) {
      const int gc = n0 + wn * 64 + ni * 16 + lr;
      float bv = 0.f;
      if (BIAS) bv = bias[gc];
      #pragma unroll
      for (int j = 0; j < 4; ++j) {
        float v = acc[mi][ni][j] + bv;
        if (GELU) v = 0.5f * v * (1.f + erff(v * 0.70710678118654752f));
        const size_t o = (size_t)(gr + j) * N + gc;
        if (WF32) Cf[o] = v;
        if (WF16) {
          const _Float16 hi = (_Float16)v;
          Chh[o] = hi;
          Chl[o] = (_Float16)(v - (float)hi);
        }
      }
    }
  }
}

// ---------------------------------------------------------------- M_part = K^T V partials
// qkv layout: [b*1024+t][3072]: q at h*64+i, k at 1024+h*64+i, v at 2048+h*64+j
__global__ __launch_bounds__(256) void ktv_kernel(const _Float16* __restrict__ qh,
                                                  const _Float16* __restrict__ ql,
                                                  float* __restrict__ Mp) {
  const int bid = blockIdx.x;            // bh*4 + q
  const int q = bid & 3, bh = bid >> 2;
  const int b = bh >> 4, h = bh & 15;
  __shared__ float Ks[8192], Vs[8192];   // [128 rows][64], exact f32
  const int tid = threadIdx.x;
  const int tq = tid >> 6;
  const int tile = tid & 63;
  const int i0 = (tile >> 3) * 8, j0 = (tile & 7) * 8;
  float acc[8][8];
  #pragma unroll
  for (int ii = 0; ii < 8; ++ii)
    #pragma unroll
    for (int jj = 0; jj < 8; ++jj) acc[ii][jj] = 0.f;

  for (int cc = 0; cc < 2; ++cc) {
    const int c = q * 2 + cc;
    for (int idx = tid * 8; idx < 8192; idx += 2048) {
      const int r = idx >> 6, kk = idx & 63;
      const size_t g = (size_t)(b * 1024 + c * 128 + r) * 3072 + h * 64 + kk;
      const half8 k_h = *(const half8*)&qh[g + 1024];
      const half8 k_l = *(const half8*)&ql[g + 1024];
      const half8 v_h = *(const half8*)&qh[g + 2048];
      const half8 v_l = *(const half8*)&ql[g + 2048];
      #pragma unroll
      for (int xx = 0; xx < 8; ++xx) {
        Ks[idx + xx] = (float)k_h[xx] + (float)k_l[xx];
        Vs[idx + xx] = (float)v_h[xx] + (float)v_l[xx];
      }
    }
    __syncthreads();
    for (int r = tq * 32; r < tq * 32 + 32; ++r) {
      float kv[8], vv[8];
      #pragma unroll
      for (int xx = 0; xx < 8; ++xx) { kv[xx] = Ks[r * 64 + i0 + xx]; vv[xx] = Vs[r * 64 + j0 + xx]; }
      #pragma unroll
      for (int ii = 0; ii < 8; ++ii)
        #pragma unroll
        for (int jj = 0; jj < 8; ++jj) acc[ii][jj] += kv[ii] * vv[jj];
    }
    __syncthreads();
  }
  __shared__ float red[64][64];
  for (int pp = 0; pp < 4; ++pp) {
    if (tq == pp) {
      #pragma unroll
      for (int ii = 0; ii < 8; ++ii)
        #pragma unroll
        for (int jj = 0; jj < 8; ++jj) {
          if (pp == 0) red[tile][ii * 8 + jj] = acc[ii][jj];
          else         red[tile][ii * 8 + jj] += acc[ii][jj];
        }
    }
    __syncthreads();
  }
  for (int o = tid; o < 4096; o += 256) {
    const int i = o >> 6, j = o & 63;
    Mp[((size_t)(q * 64 + bh) << 12) + o] = red[(i >> 3) * 8 + (j >> 3)][(i & 7) * 8 + (j & 7)];
  }
}

// ---------------------------------------------------------------- av = scale * Q @ M -> f16 hi/lo
__global__ __launch_bounds__(256) void av_kernel(const _Float16* __restrict__ qh,
                                                 const _Float16* __restrict__ ql,
                                                 const float* __restrict__ Mp,
                                                 _Float16* __restrict__ avh,
                                                 _Float16* __restrict__ avl) {
  const int id = blockIdx.x;             // bh*8 + tc
  const int tc = id & 7, bh = id >> 3;
  const int b = bh >> 4, h = bh & 15;
  __shared__ float Ms[4096];             // [64 i][64 j]
  __shared__ float Qs[8192];             // [128 rows][64]
  const int tid = threadIdx.x;
  for (int o = tid * 4; o < 4096; o += 1024) {
    const f32x4 p0 = *(const f32x4*)&Mp[((size_t)(bh) << 12) + o];
    const f32x4 p1 = *(const f32x4*)&Mp[((size_t)(64 + bh) << 12) + o];
    const f32x4 p2 = *(const f32x4*)&Mp[((size_t)(128 + bh) << 12) + o];
    const f32x4 p3 = *(const f32x4*)&Mp[((size_t)(192 + bh) << 12) + o];
    f32x4 m;
    #pragma unroll
    for (int c = 0; c < 4; ++c) m[c] = 0.125f * (p0[c] + p1[c] + p2[c] + p3[c]);
    *(f32x4*)&Ms[o] = m;
  }
  for (int idx = tid * 8; idx < 8192; idx += 2048) {
    const int r = idx >> 6, kk = idx & 63;
    const size_t g = (size_t)(b * 1024 + tc * 128 + r) * 3072 + h * 64 + kk;
    const half8 q_h = *(const half8*)&qh[g];
    const half8 q_l = *(const half8*)&ql[g];
    #pragma unroll
    for (int xx = 0; xx < 8; ++xx) Qs[idx + xx] = (float)q_h[xx] + (float)q_l[xx];
  }
  __syncthreads();
  const int r0 = (tid >> 3) * 4, j0 = (tid & 7) * 8;
  float acc[4][8];
  #pragma unroll
  for (int rr = 0; rr < 4; ++rr)
    #pragma unroll
    for (int jj = 0; jj < 8; ++jj) acc[rr][jj] = 0.f;
  for (int i = 0; i < 64; ++i) {
    float m8[8];
    #pragma unroll
    for (int jj = 0; jj < 8; ++jj) m8[jj] = Ms[i * 64 + j0 + jj];
    #pragma unroll
    for (int rr = 0; rr < 4; ++rr) {
      const float qv = Qs[(r0 + rr) * 64 + i];
      #pragma unroll
      for (int jj = 0; jj < 8; ++jj) acc[rr][jj] += qv * m8[jj];
    }
  }
  #pragma unroll
  for (int rr = 0; rr < 4; ++rr)
    #pragma unroll
    for (int jj = 0; jj < 8; ++jj) {
      const size_t o = (size_t)(b * 1024 + tc * 128 + r0 + rr) * 1024 + h * 64 + j0 + jj;
      const float v = acc[rr][jj];
      const _Float16 hi = (_Float16)v;
      avh[o] = hi;
      avl[o] = (_Float16)(v - (float)hi);
    }
}

// ---------------------------------------------------------------- final head, split-K
__global__ __launch_bounds__(256) void pred_split1(const float* __restrict__ x,
                                                   const float* __restrict__ Wp,
                                                   float* __restrict__ partial) {
  const int bid = blockIdx.x;            // b*512 + a*64 + sp
  const int b = bid >> 9, a = (bid >> 6) & 7, sp = bid & 63;
  const int tid = threadIdx.x;
  const int base = sp * 8192;            // elems [base, base+8192)
  float acc = 0.f;
  #pragma unroll
  for (int it = 0; it < 8; ++it) {
    const int i4 = base + it * 1024 + tid * 4;
    const int s = i4 >> 10, d = i4 & 1023;
    const f32x4 xv = *(const f32x4*)&x[(size_t)(b * 1024 + 2 * s + 1) * 1024 + d];
    const f32x4 wv = *(const f32x4*)&Wp[(size_t)a * 524288 + i4];
    acc += xv[0] * wv[0] + xv[1] * wv[1] + xv[2] * wv[2] + xv[3] * wv[3];
  }
  #pragma unroll
  for (int off = 32; off; off >>= 1) acc += __shfl_down(acc, off);
  __shared__ float red[4];
  const int wid = tid >> 6, lane = tid & 63;
  if (!lane) red[wid] = acc;
  __syncthreads();
  if (tid == 0) partial[bid] = red[0] + red[1] + red[2] + red[3];
}

__global__ __launch_bounds__(64) void pred_split2(const float* __restrict__ partial,
                                                  const float* __restrict__ bp,
                                                  float* __restrict__ out) {
  const int pair = blockIdx.x;           // b*8 + a
  const int lane = threadIdx.x;
  float v = partial[pair * 64 + lane];
  #pragma unroll
  for (int off = 32; off; off >>= 1) v += __shfl_down(v, off);
  if (lane == 0) out[pair] = tanhf(v + bp[pair & 7]);
}

// ---------------------------------------------------------------- host
extern "C" void kernel_launch(void* const* d_in, const int* in_sizes, int n_in,
                              void* d_out, int out_size, void* d_ws, size_t ws_size,
                              hipStream_t stream) {
  (void)in_sizes; (void)n_in; (void)out_size; (void)ws_size;
  const float* obs    = (const float*)d_in[0];
  const float* act    = (const float*)d_in[1];
  // d_in[2] attn_mask: all ones -> no-op mask, unused
  const float* W_obs  = (const float*)d_in[3];
  const float* b_obs  = (const float*)d_in[4];
  const float* W_act  = (const float*)d_in[5];
  const float* b_act  = (const float*)d_in[6];
  const float* ln0_g  = (const float*)d_in[7];
  const float* ln0_b  = (const float*)d_in[8];
  const float* Wq     = (const float*)d_in[9];
  const float* Wk     = (const float*)d_in[10];
  const float* Wv     = (const float*)d_in[11];
  const float* Wo     = (const float*)d_in[12];
  const float* bo     = (const float*)d_in[13];
  const float* ln1_g  = (const float*)d_in[14];
  const float* ln1_b  = (const float*)d_in[15];
  const float* Wf1    = (const float*)d_in[16];
  const float* bf1    = (const float*)d_in[17];
  const float* Wf2    = (const float*)d_in[18];
  const float* bf2    = (const float*)d_in[19];
  const float* W_pred = (const float*)d_in[20];
  const float* b_pred = (const float*)d_in[21];
  float* out = (float*)d_out;

  char* p = (char*)d_ws;
  auto alloc = [&](size_t bytes) { char* r = p; p += (bytes + 255) & ~(size_t)255; return r; };
  const size_t MB = 1024 * 1024;
  _Float16* whqkv_h = (_Float16*)alloc(6 * MB);
  _Float16* whqkv_l = (_Float16*)alloc(6 * MB);
  _Float16* who_h   = (_Float16*)alloc(2 * MB);
  _Float16* who_l   = (_Float16*)alloc(2 * MB);
  _Float16* whf1_h  = (_Float16*)alloc(8 * MB);
  _Float16* whf1_l  = (_Float16*)alloc(8 * MB);
  _Float16* whf2_h  = (_Float16*)alloc(8 * MB);
  _Float16* whf2_l  = (_Float16*)alloc(8 * MB);
  float*    e       = (float*)alloc(16 * MB);   // embed; later aliased as attn_out
  float*    x       = (float*)alloc(16 * MB);
  _Float16* xh_h    = (_Float16*)alloc(8 * MB);
  _Float16* xh_l    = (_Float16*)alloc(8 * MB);
  _Float16* av_h    = (_Float16*)alloc(8 * MB);
  _Float16* av_l    = (_Float16*)alloc(8 * MB);
  _Float16* h1_h    = (_Float16*)alloc(8 * MB);
  _Float16* h1_l    = (_Float16*)alloc(8 * MB);
  float*    Mp      = (float*)alloc(4 * MB);
  float*    pred_p  = (float*)alloc(2048 * 4);
  char*     U       = alloc(64 * MB);           // union: qkv pair | fh pair (disjoint lifetimes)
  _Float16* qkv_h = (_Float16*)U;
  _Float16* qkv_l = (_Float16*)(U + 24 * MB);
  _Float16* fh_h  = (_Float16*)U;
  _Float16* fh_l  = (_Float16*)(U + 32 * MB);
  float* ao = e;

  auto f2h = [&](const float* s, _Float16* hh, _Float16* ll, int n) {
    int blocks = (n / 4 + 255) / 256; if (blocks > 2048) blocks = 2048;
    f2h_split_kernel<<<blocks, 256, 0, stream>>>(s, hh, ll, n);
  };

  embed_kernel<<<4096, 256, 0, stream>>>(obs, act, W_obs, b_obs, W_act, b_act, e);
  ln_kernel<false, true><<<4096, 256, 0, stream>>>(e, nullptr, ln0_g, ln0_b, x, xh_h, xh_l);

  for (int l = 0; l < 6; ++l) {
    const size_t dd = (size_t)l * 1024 * 1024, df = (size_t)l * 4096 * 1024;
    f2h(Wq + dd, whqkv_h,           whqkv_l,           1048576);
    f2h(Wk + dd, whqkv_h + 1048576, whqkv_l + 1048576, 1048576);
    f2h(Wv + dd, whqkv_h + 2097152, whqkv_l + 2097152, 1048576);
    f2h(Wo + dd, who_h,  who_l,  1048576);
    f2h(Wf1 + df, whf1_h, whf1_l, 4194304);
    f2h(Wf2 + df, whf2_h, whf2_l, 4194304);

    // qkv = x @ [Wq;Wk;Wv]^T   (M=4096, N=3072, K=1024)
    gemm_bt<false, false, false, true><<<dim3(24, 32), 256, 0, stream>>>(
        xh_h, xh_l, whqkv_h, whqkv_l, nullptr, nullptr, qkv_h, qkv_l, 4096, 3072, 1024);
    // M = K^T V partials, then av = scale * Q @ M
    ktv_kernel<<<256, 256, 0, stream>>>(qkv_h, qkv_l, Mp);
    av_kernel<<<512, 256, 0, stream>>>(qkv_h, qkv_l, Mp, av_h, av_l);
    // attn_out = av @ Wo^T + bo
    gemm_bt<true, false, true, false><<<dim3(8, 32), 256, 0, stream>>>(
        av_h, av_l, who_h, who_l, bo + (size_t)l * 1024, ao, nullptr, nullptr, 4096, 1024, 1024);
    // h1 = LN(x + attn_out)
    ln_kernel<true, false><<<4096, 256, 0, stream>>>(
        x, ao, ln1_g + (size_t)l * 1024, ln1_b + (size_t)l * 1024, nullptr, h1_h, h1_l);
    // f = gelu(h1 @ Wf1^T + bf1)
    gemm_bt<true, true, false, true><<<dim3(32, 32), 256, 0, stream>>>(
        h1_h, h1_l, whf1_h, whf1_l, bf1 + (size_t)l * 4096, nullptr, fh_h, fh_l, 4096, 4096, 1024);
    // x = f @ Wf2^T + bf2
    gemm_bt<true, false, true, true><<<dim3(8, 32), 256, 0, stream>>>(
        fh_h, fh_l, whf2_h, whf2_l, bf2 + (size_t)l * 1024, x, xh_h, xh_l, 4096, 1024, 4096);
  }

  pred_split1<<<2048, 256, 0, stream>>>(x, W_pred, pred_p);
  pred_split2<<<32, 64, 0, stream>>>(pred_p, b_pred, out);
}

// Round 10
// 2607.367 us; speedup vs baseline: 1.0954x; 1.0954x over previous
//
#include <hip/hip_runtime.h>

typedef __attribute__((ext_vector_type(8))) _Float16 half8;
typedef __attribute__((ext_vector_type(4))) _Float16 half4v;
typedef __attribute__((ext_vector_type(4))) float f32x4;

// ---------------------------------------------------------------- utilities
__device__ __forceinline__ void gload16(const void* g, void* l) {
  __builtin_amdgcn_global_load_lds((__attribute__((address_space(1))) void*)(g),
                                   (__attribute__((address_space(3))) void*)(l), 16, 0, 0);
}

// ---------------------------------------------------------------- embed + PE (round-5 version, 137us known)
__global__ __launch_bounds__(256) void embed_kernel(
    const float* __restrict__ obs, const float* __restrict__ act,
    const float* __restrict__ W_obs, const float* __restrict__ b_obs,
    const float* __restrict__ W_act, const float* __restrict__ b_act,
    float* __restrict__ e) {
  const int row = blockIdx.x;            // b*1024 + t
  const int b = row >> 10, t = row & 1023;
  const int pos = t >> 1;
  const bool is_act = t & 1;
  __shared__ float in_row[64];
  const int tid = threadIdx.x;
  if (!is_act) { if (tid < 64) in_row[tid] = obs[(size_t)(b * 512 + pos) * 64 + tid]; }
  else         { if (tid < 8)  in_row[tid] = act[(size_t)(b * 512 + pos) * 8 + tid]; }
  __syncthreads();
  for (int d = tid; d < 1024; d += 256) {
    float acc;
    if (!is_act) {
      acc = b_obs[d];
      const float* w = &W_obs[d * 64];
      #pragma unroll 8
      for (int c = 0; c < 64; ++c) acc += in_row[c] * w[c];
    } else {
      acc = b_act[d];
      const float* w = &W_act[d * 8];
      #pragma unroll
      for (int c = 0; c < 8; ++c) acc += in_row[c] * w[c];
    }
    const int j = d >> 1;
    const float dv = expf((float)(2 * j) * (-9.210340371976184f / 1024.0f));
    const float ang = (float)pos * dv;
    acc += (d & 1) ? cosf(ang) : sinf(ang);
    e[(size_t)row * 1024 + d] = acc;
  }
}

// ---------------------------------------------------------------- layernorm -> f32(opt) + f16 hi/lo
template<bool RES, bool WF32>
__global__ __launch_bounds__(256) void ln_kernel(
    const float* __restrict__ in, const float* __restrict__ res,
    const float* __restrict__ g, const float* __restrict__ bta,
    float* __restrict__ of, _Float16* __restrict__ ohh, _Float16* __restrict__ ohl) {
  const int row = blockIdx.x;
  const size_t base = (size_t)row * 1024;
  const int tid = threadIdx.x;
  float v[4];
  {
    const f32x4 a = *(const f32x4*)&in[base + tid * 4];
    if (RES) {
      const f32x4 r = *(const f32x4*)&res[base + tid * 4];
      v[0] = a[0] + r[0]; v[1] = a[1] + r[1]; v[2] = a[2] + r[2]; v[3] = a[3] + r[3];
    } else {
      v[0] = a[0]; v[1] = a[1]; v[2] = a[2]; v[3] = a[3];
    }
  }
  float s = 0.f, sq = 0.f;
  #pragma unroll
  for (int c = 0; c < 4; ++c) { s += v[c]; sq += v[c] * v[c]; }
  #pragma unroll
  for (int off = 32; off; off >>= 1) { s += __shfl_down(s, off); sq += __shfl_down(sq, off); }
  __shared__ float rs[4], rq[4];
  const int wid = tid >> 6, lane = tid & 63;
  if (!lane) { rs[wid] = s; rq[wid] = sq; }
  __syncthreads();
  s = rs[0] + rs[1] + rs[2] + rs[3];
  sq = rq[0] + rq[1] + rq[2] + rq[3];
  const float mean = s * (1.f / 1024.f);
  const float var = sq * (1.f / 1024.f) - mean * mean;
  const float rstd = rsqrtf(var + 1e-5f);
  #pragma unroll
  for (int c = 0; c < 4; ++c) {
    const int d = tid * 4 + c;
    const float o = (v[c] - mean) * rstd * g[d] + bta[d];
    if (WF32) of[base + d] = o;
    const _Float16 hi = (_Float16)o;
    ohh[base + d] = hi;
    ohl[base + d] = (_Float16)(o - (float)hi);
  }
}

// ---------------------------------------------------------------- f32 -> f16 hi/lo split
__global__ __launch_bounds__(256) void f2h_split_kernel(const float* __restrict__ s,
                                                        _Float16* __restrict__ hi,
                                                        _Float16* __restrict__ lo, int n) {
  int i = (blockIdx.x * 256 + threadIdx.x) * 4;
  const int stride = gridDim.x * 256 * 4;
  for (; i < n; i += stride) {
    const f32x4 v = *(const f32x4*)&s[i];
    half4v h, l;
    #pragma unroll
    for (int c = 0; c < 4; ++c) {
      h[c] = (_Float16)v[c];
      l[c] = (_Float16)(v[c] - (float)h[c]);
    }
    *(half4v*)&hi[i] = h;
    *(half4v*)&lo[i] = l;
  }
}

// ---------------------------------------------------------------- 128^2 split-f16 GEMM (round-7 loop) for wo/ff2
template<bool BIAS, bool GELU, bool WF32, bool WF16>
__global__ __launch_bounds__(256, 2) void gemm_bt(
    const _Float16* __restrict__ Ah, const _Float16* __restrict__ Al,
    const _Float16* __restrict__ Bh, const _Float16* __restrict__ Bl,
    const float* __restrict__ bias,
    float* __restrict__ Cf, _Float16* __restrict__ Chh, _Float16* __restrict__ Chl,
    const int M, const int N, const int K) {
  __shared__ _Float16 lds[2][4][4096];
  const int tid = threadIdx.x;
  const int wid = tid >> 6, lane = tid & 63;
  const int wm = wid >> 1, wn = wid & 1;
  const int nwg = gridDim.x * gridDim.y;
  int flat = blockIdx.y * gridDim.x + blockIdx.x;
  flat = (flat & 7) * (nwg >> 3) + (flat >> 3);
  const int m0 = (flat / gridDim.x) * 128, n0 = (flat % gridDim.x) * 128;
  const int KT = K >> 5;

  f32x4 acc[4][4];
  #pragma unroll
  for (int i = 0; i < 4; ++i)
    #pragma unroll
    for (int j = 0; j < 4; ++j) acc[i][j] = f32x4{0.f, 0.f, 0.f, 0.f};

  const int ho0 = wid * 512 + lane * 8;
  const int r0s = ho0 >> 5, kk0 = ho0 & 31;
  const int ho1 = (wid + 4) * 512 + lane * 8;
  const int r1s = ho1 >> 5, kk1 = ho1 & 31;

  auto stage = [&](int buf, int kt) {
    const int k0 = kt << 5;
    const size_t a0 = (size_t)(m0 + r0s) * K + k0 + kk0;
    const size_t a1 = (size_t)(m0 + r1s) * K + k0 + kk1;
    const size_t b0 = (size_t)(n0 + r0s) * K + k0 + kk0;
    const size_t b1 = (size_t)(n0 + r1s) * K + k0 + kk1;
    gload16(Ah + a0, &lds[buf][0][ho0]); gload16(Ah + a1, &lds[buf][0][ho1]);
    gload16(Al + a0, &lds[buf][1][ho0]); gload16(Al + a1, &lds[buf][1][ho1]);
    gload16(Bh + b0, &lds[buf][2][ho0]); gload16(Bh + b1, &lds[buf][2][ho1]);
    gload16(Bl + b0, &lds[buf][3][ho0]); gload16(Bl + b1, &lds[buf][3][ho1]);
  };

  stage(0, 0);
  int cur = 0;
  const int lr = lane & 15, lk = (lane >> 4) * 8;
  for (int kt = 0; kt < KT; ++kt) {
    __syncthreads();
    if (kt + 1 < KT) stage(cur ^ 1, kt + 1);
    const _Float16* lAh = &lds[cur][0][0];
    const _Float16* lAl = &lds[cur][1][0];
    const _Float16* lBh = &lds[cur][2][0];
    const _Float16* lBl = &lds[cur][3][0];
    half8 afh[4], afl[4], bfh[4], bfl[4];
    #pragma unroll
    for (int mi = 0; mi < 4; ++mi) {
      const int o = (wm * 64 + mi * 16 + lr) * 32 + lk;
      afh[mi] = *(const half8*)&lAh[o];
      afl[mi] = *(const half8*)&lAl[o];
    }
    #pragma unroll
    for (int ni = 0; ni < 4; ++ni) {
      const int o = (wn * 64 + ni * 16 + lr) * 32 + lk;
      bfh[ni] = *(const half8*)&lBh[o];
      bfl[ni] = *(const half8*)&lBl[o];
    }
    #pragma unroll
    for (int mi = 0; mi < 4; ++mi)
      #pragma unroll
      for (int ni = 0; ni < 4; ++ni) {
        acc[mi][ni] = __builtin_amdgcn_mfma_f32_16x16x32_f16(afh[mi], bfh[ni], acc[mi][ni], 0, 0, 0);
        acc[mi][ni] = __builtin_amdgcn_mfma_f32_16x16x32_f16(afl[mi], bfh[ni], acc[mi][ni], 0, 0, 0);
        acc[mi][ni] = __builtin_amdgcn_mfma_f32_16x16x32_f16(afh[mi], bfl[ni], acc[mi][ni], 0, 0, 0);
      }
    cur ^= 1;
  }

  const int lq = lane >> 4;
  #pragma unroll
  for (int mi = 0; mi < 4; ++mi) {
    const int gr = m0 + wm * 64 + mi * 16 + lq * 4;
    #pragma unroll
    for (int ni = 0; ni < 4; ++ni) {
      const int gc = n0 + wn * 64 + ni * 16 + lr;
      float bv = 0.f;
      if (BIAS) bv = bias[gc];
      #pragma unroll
      for (int j = 0; j < 4; ++j) {
        float v = acc[mi][ni][j] + bv;
        if (GELU) v = 0.5f * v * (1.f + erff(v * 0.70710678118654752f));
        const size_t o = (size_t)(gr + j) * N + gc;
        if (WF32) Cf[o] = v;
        if (WF16) {
          const _Float16 hi = (_Float16)v;
          Chh[o] = hi;
          Chl[o] = (_Float16)(v - (float)hi);
        }
      }
    }
  }
}

// ---------------------------------------------------------------- 256^2 phase-split split-f16 GEMM (qkv/ff1)
// 8 waves (2x4), BK=32, LDS 128KiB double-buffered [buf][Ah/Al/Bh/Bl][256*32].
// Phases per K-tile: A=Ah*Bh, B=Al*Bh, C=Ah*Bl; halves H={Ah,Bh}(4 loads/thr), L={Al,Bl}(4).
// Counted vmcnt(4) pipeline: H(t) waited at top (L(t) in flight), L(t) waited at B-top (H(t+1) in flight).
// LDS chunk-XOR swizzle c^=(row>>1)&3 applied to global SOURCE (gload_lds dest stays linear) and ds_read addr.
template<bool BIAS, bool GELU>
__global__ __launch_bounds__(512, 2) void gemm256(
    const _Float16* __restrict__ Ah, const _Float16* __restrict__ Al,
    const _Float16* __restrict__ Bh, const _Float16* __restrict__ Bl,
    const float* __restrict__ bias,
    _Float16* __restrict__ Chh, _Float16* __restrict__ Chl,
    const int N, const int K) {
  __shared__ _Float16 lds[2][4][8192];   // 128 KiB
  const int tid = threadIdx.x;
  const int wid = tid >> 6, lane = tid & 63;
  const int wm = wid >> 2, wn = wid & 3;          // 2 x 4 wave grid; wave owns 128x64
  const int nwg = gridDim.x * gridDim.y;
  int flat = blockIdx.y * gridDim.x + blockIdx.x;
  flat = (flat & 7) * (nwg >> 3) + (flat >> 3);   // XCD swizzle (grids % 8 == 0)
  const int m0 = (flat / gridDim.x) * 256, n0 = (flat % gridDim.x) * 256;
  const int KT = K >> 5;
  const int lr = lane & 15, rch = lane >> 4;

  // precomputed swizzled read offsets (halfs within one tensor plane)
  int aoff[8], boff[4];
  #pragma unroll
  for (int m = 0; m < 8; ++m) {
    const int row = wm * 128 + m * 16 + lr;
    aoff[m] = row * 32 + ((rch ^ ((row >> 1) & 3)) << 3);
  }
  #pragma unroll
  for (int n = 0; n < 4; ++n) {
    const int row = wn * 64 + n * 16 + lr;
    boff[n] = row * 32 + ((rch ^ ((row >> 1) & 3)) << 3);
  }
  // staging: chunk ci = j*512 + wid*64 + lane; LDS dest linear ci*16B; source col pre-swizzled
  int soff[2]; size_t sA[2], sB[2];
  #pragma unroll
  for (int j = 0; j < 2; ++j) {
    const int ci = j * 512 + wid * 64 + lane;
    const int row = ci >> 2;
    const int cs = (((ci & 3) ^ ((row >> 1) & 3)) << 3);
    soff[j] = ci * 8;
    sA[j] = (size_t)(m0 + row) * K + cs;
    sB[j] = (size_t)(n0 + row) * K + cs;
  }

  f32x4 acc[8][4];
  #pragma unroll
  for (int m = 0; m < 8; ++m)
    #pragma unroll
    for (int n = 0; n < 4; ++n) acc[m][n] = f32x4{0.f, 0.f, 0.f, 0.f};

  auto stH = [&](int nb, int kt) {
    const int k0 = kt << 5;
    gload16(Ah + sA[0] + k0, &lds[nb][0][soff[0]]);
    gload16(Ah + sA[1] + k0, &lds[nb][0][soff[1]]);
    gload16(Bh + sB[0] + k0, &lds[nb][2][soff[0]]);
    gload16(Bh + sB[1] + k0, &lds[nb][2][soff[1]]);
  };
  auto stAl = [&](int nb, int kt) {
    const int k0 = kt << 5;
    gload16(Al + sA[0] + k0, &lds[nb][1][soff[0]]);
    gload16(Al + sA[1] + k0, &lds[nb][1][soff[1]]);
  };
  auto stBl = [&](int nb, int kt) {
    const int k0 = kt << 5;
    gload16(Bl + sB[0] + k0, &lds[nb][3][soff[0]]);
    gload16(Bl + sB[1] + k0, &lds[nb][3][soff[1]]);
  };

  stH(0, 0); stAl(0, 0); stBl(0, 0);   // queue: [H0(4), L0(4)]

  for (int t = 0; t < KT; ++t) {
    const int buf = t & 1, nb = buf ^ 1;
    const bool pf = (t + 1 < KT);
    // ---- PHASE A: Ah*Bh ----
    asm volatile("s_waitcnt vmcnt(4)" ::: "memory");    // H(t) landed; L(t) in flight
    __builtin_amdgcn_s_barrier();
    __builtin_amdgcn_sched_barrier(0);
    half8 ah[8], bh8[4], al[8], bl8[4];
    #pragma unroll
    for (int m = 0; m < 8; ++m) ah[m] = *(const half8*)&lds[buf][0][aoff[m]];
    #pragma unroll
    for (int n = 0; n < 4; ++n) bh8[n] = *(const half8*)&lds[buf][2][boff[n]];
    if (pf) stH(nb, t + 1);
    asm volatile("s_waitcnt lgkmcnt(0)" ::: "memory");
    __builtin_amdgcn_sched_barrier(0);
    __builtin_amdgcn_s_setprio(1);
    #pragma unroll
    for (int m = 0; m < 8; ++m)
      #pragma unroll
      for (int n = 0; n < 4; ++n)
        acc[m][n] = __builtin_amdgcn_mfma_f32_16x16x32_f16(ah[m], bh8[n], acc[m][n], 0, 0, 0);
    __builtin_amdgcn_s_setprio(0);
    // ---- PHASE B: Al*Bh ----
    if (pf) { asm volatile("s_waitcnt vmcnt(4)" ::: "memory"); }   // L(t) landed; H(t+1) in flight
    else    { asm volatile("s_waitcnt vmcnt(0)" ::: "memory"); }
    __builtin_amdgcn_s_barrier();
    __builtin_amdgcn_sched_barrier(0);
    #pragma unroll
    for (int m = 0; m < 8; ++m) al[m] = *(const half8*)&lds[buf][1][aoff[m]];
    if (pf) stAl(nb, t + 1);
    asm volatile("s_waitcnt lgkmcnt(0)" ::: "memory");
    __builtin_amdgcn_sched_barrier(0);
    __builtin_amdgcn_s_setprio(1);
    #pragma unroll
    for (int m = 0; m < 8; ++m)
      #pragma unroll
      for (int n = 0; n < 4; ++n)
        acc[m][n] = __builtin_amdgcn_mfma_f32_16x16x32_f16(al[m], bh8[n], acc[m][n], 0, 0, 0);
    __builtin_amdgcn_s_setprio(0);
    // ---- PHASE C: Ah*Bl ----
    #pragma unroll
    for (int n = 0; n < 4; ++n) bl8[n] = *(const half8*)&lds[buf][3][boff[n]];
    if (pf) stBl(nb, t + 1);
    asm volatile("s_waitcnt lgkmcnt(0)" ::: "memory");
    __builtin_amdgcn_sched_barrier(0);
    __builtin_amdgcn_s_setprio(1);
    #pragma unroll
    for (int m = 0; m < 8; ++m)
      #pragma unroll
      for (int n = 0; n < 4; ++n)
        acc[m][n] = __builtin_amdgcn_mfma_f32_16x16x32_f16(ah[m], bl8[n], acc[m][n], 0, 0, 0);
    __builtin_amdgcn_s_setprio(0);
    __builtin_amdgcn_s_barrier();    // end of tile: all reads of buf done (lgkm0 above)
  }

  const int lq = lane >> 4;
  #pragma unroll
  for (int m = 0; m < 8; ++m) {
    const int gr = m0 + wm * 128 + m * 16 + lq * 4;
    #pragma unroll
    for (int n = 0; n < 4; ++n) {
      const int gc = n0 + wn * 64 + n * 16 + lr;
      float bv = 0.f;
      if (BIAS) bv = bias[gc];
      #pragma unroll
      for (int j = 0; j < 4; ++j) {
        float v = acc[m][n][j] + bv;
        if (GELU) v = 0.5f * v * (1.f + erff(v * 0.70710678118654752f));
        const size_t o = (size_t)(gr + j) * N + gc;
        const _Float16 hi = (_Float16)v;
        Chh[o] = hi;
        Chl[o] = (_Float16)(v - (float)hi);
      }
    }
  }
}

// ---------------------------------------------------------------- M_part = K^T V partials
__global__ __launch_bounds__(256) void ktv_kernel(const _Float16* __restrict__ qh,
                                                  const _Float16* __restrict__ ql,
                                                  float* __restrict__ Mp) {
  const int bid = blockIdx.x;            // bh*4 + q
  const int q = bid & 3, bh = bid >> 2;
  const int b = bh >> 4, h = bh & 15;
  __shared__ float Ks[8192], Vs[8192];
  const int tid = threadIdx.x;
  const int tq = tid >> 6;
  const int tile = tid & 63;
  const int i0 = (tile >> 3) * 8, j0 = (tile & 7) * 8;
  float acc[8][8];
  #pragma unroll
  for (int ii = 0; ii < 8; ++ii)
    #pragma unroll
    for (int jj = 0; jj < 8; ++jj) acc[ii][jj] = 0.f;

  for (int cc = 0; cc < 2; ++cc) {
    const int c = q * 2 + cc;
    for (int idx = tid * 8; idx < 8192; idx += 2048) {
      const int r = idx >> 6, kk = idx & 63;
      const size_t g = (size_t)(b * 1024 + c * 128 + r) * 3072 + h * 64 + kk;
      const half8 k_h = *(const half8*)&qh[g + 1024];
      const half8 k_l = *(const half8*)&ql[g + 1024];
      const half8 v_h = *(const half8*)&qh[g + 2048];
      const half8 v_l = *(const half8*)&ql[g + 2048];
      #pragma unroll
      for (int xx = 0; xx < 8; ++xx) {
        Ks[idx + xx] = (float)k_h[xx] + (float)k_l[xx];
        Vs[idx + xx] = (float)v_h[xx] + (float)v_l[xx];
      }
    }
    __syncthreads();
    for (int r = tq * 32; r < tq * 32 + 32; ++r) {
      float kv[8], vv[8];
      #pragma unroll
      for (int xx = 0; xx < 8; ++xx) { kv[xx] = Ks[r * 64 + i0 + xx]; vv[xx] = Vs[r * 64 + j0 + xx]; }
      #pragma unroll
      for (int ii = 0; ii < 8; ++ii)
        #pragma unroll
        for (int jj = 0; jj < 8; ++jj) acc[ii][jj] += kv[ii] * vv[jj];
    }
    __syncthreads();
  }
  __shared__ float red[64][64];
  for (int pp = 0; pp < 4; ++pp) {
    if (tq == pp) {
      #pragma unroll
      for (int ii = 0; ii < 8; ++ii)
        #pragma unroll
        for (int jj = 0; jj < 8; ++jj) {
          if (pp == 0) red[tile][ii * 8 + jj] = acc[ii][jj];
          else         red[tile][ii * 8 + jj] += acc[ii][jj];
        }
    }
    __syncthreads();
  }
  for (int o = tid; o < 4096; o += 256) {
    const int i = o >> 6, j = o & 63;
    Mp[((size_t)(q * 64 + bh) << 12) + o] = red[(i >> 3) * 8 + (j >> 3)][(i & 7) * 8 + (j & 7)];
  }
}

// ---------------------------------------------------------------- av = scale * Q @ M -> f16 hi/lo
__global__ __launch_bounds__(256) void av_kernel(const _Float16* __restrict__ qh,
                                                 const _Float16* __restrict__ ql,
                                                 const float* __restrict__ Mp,
                                                 _Float16* __restrict__ avh,
                                                 _Float16* __restrict__ avl) {
  const int id = blockIdx.x;             // bh*8 + tc
  const int tc = id & 7, bh = id >> 3;
  const int b = bh >> 4, h = bh & 15;
  __shared__ float Ms[4096];
  __shared__ float Qs[8192];
  const int tid = threadIdx.x;
  for (int o = tid * 4; o < 4096; o += 1024) {
    const f32x4 p0 = *(const f32x4*)&Mp[((size_t)(bh) << 12) + o];
    const f32x4 p1 = *(const f32x4*)&Mp[((size_t)(64 + bh) << 12) + o];
    const f32x4 p2 = *(const f32x4*)&Mp[((size_t)(128 + bh) << 12) + o];
    const f32x4 p3 = *(const f32x4*)&Mp[((size_t)(192 + bh) << 12) + o];
    f32x4 m;
    #pragma unroll
    for (int c = 0; c < 4; ++c) m[c] = 0.125f * (p0[c] + p1[c] + p2[c] + p3[c]);
    *(f32x4*)&Ms[o] = m;
  }
  for (int idx = tid * 8; idx < 8192; idx += 2048) {
    const int r = idx >> 6, kk = idx & 63;
    const size_t g = (size_t)(b * 1024 + tc * 128 + r) * 3072 + h * 64 + kk;
    const half8 q_h = *(const half8*)&qh[g];
    const half8 q_l = *(const half8*)&ql[g];
    #pragma unroll
    for (int xx = 0; xx < 8; ++xx) Qs[idx + xx] = (float)q_h[xx] + (float)q_l[xx];
  }
  __syncthreads();
  const int r0 = (tid >> 3) * 4, j0 = (tid & 7) * 8;
  float acc[4][8];
  #pragma unroll
  for (int rr = 0; rr < 4; ++rr)
    #pragma unroll
    for (int jj = 0; jj < 8; ++jj) acc[rr][jj] = 0.f;
  for (int i = 0; i < 64; ++i) {
    float m8[8];
    #pragma unroll
    for (int jj = 0; jj < 8; ++jj) m8[jj] = Ms[i * 64 + j0 + jj];
    #pragma unroll
    for (int rr = 0; rr < 4; ++rr) {
      const float qv = Qs[(r0 + rr) * 64 + i];
      #pragma unroll
      for (int jj = 0; jj < 8; ++jj) acc[rr][jj] += qv * m8[jj];
    }
  }
  #pragma unroll
  for (int rr = 0; rr < 4; ++rr)
    #pragma unroll
    for (int jj = 0; jj < 8; ++jj) {
      const size_t o = (size_t)(b * 1024 + tc * 128 + r0 + rr) * 1024 + h * 64 + j0 + jj;
      const float v = acc[rr][jj];
      const _Float16 hi = (_Float16)v;
      avh[o] = hi;
      avl[o] = (_Float16)(v - (float)hi);
    }
}

// ---------------------------------------------------------------- final head, split-K
__global__ __launch_bounds__(256) void pred_split1(const float* __restrict__ x,
                                                   const float* __restrict__ Wp,
                                                   float* __restrict__ partial) {
  const int bid = blockIdx.x;            // b*512 + a*64 + sp
  const int b = bid >> 9, a = (bid >> 6) & 7, sp = bid & 63;
  const int tid = threadIdx.x;
  const int base = sp * 8192;
  float acc = 0.f;
  #pragma unroll
  for (int it = 0; it < 8; ++it) {
    const int i4 = base + it * 1024 + tid * 4;
    const int s = i4 >> 10, d = i4 & 1023;
    const f32x4 xv = *(const f32x4*)&x[(size_t)(b * 1024 + 2 * s + 1) * 1024 + d];
    const f32x4 wv = *(const f32x4*)&Wp[(size_t)a * 524288 + i4];
    acc += xv[0] * wv[0] + xv[1] * wv[1] + xv[2] * wv[2] + xv[3] * wv[3];
  }
  #pragma unroll
  for (int off = 32; off; off >>= 1) acc += __shfl_down(acc, off);
  __shared__ float red[4];
  const int wid = tid >> 6, lane = tid & 63;
  if (!lane) red[wid] = acc;
  __syncthreads();
  if (tid == 0) partial[bid] = red[0] + red[1] + red[2] + red[3];
}

__global__ __launch_bounds__(64) void pred_split2(const float* __restrict__ partial,
                                                  const float* __restrict__ bp,
                                                  float* __restrict__ out) {
  const int pair = blockIdx.x;           // b*8 + a
  const int lane = threadIdx.x;
  float v = partial[pair * 64 + lane];
  #pragma unroll
  for (int off = 32; off; off >>= 1) v += __shfl_down(v, off);
  if (lane == 0) out[pair] = tanhf(v + bp[pair & 7]);
}

// ---------------------------------------------------------------- host
extern "C" void kernel_launch(void* const* d_in, const int* in_sizes, int n_in,
                              void* d_out, int out_size, void* d_ws, size_t ws_size,
                              hipStream_t stream) {
  (void)in_sizes; (void)n_in; (void)out_size; (void)ws_size;
  const float* obs    = (const float*)d_in[0];
  const float* act    = (const float*)d_in[1];
  // d_in[2] attn_mask: all ones -> no-op mask, unused
  const float* W_obs  = (const float*)d_in[3];
  const float* b_obs  = (const float*)d_in[4];
  const float* W_act  = (const float*)d_in[5];
  const float* b_act  = (const float*)d_in[6];
  const float* ln0_g  = (const float*)d_in[7];
  const float* ln0_b  = (const float*)d_in[8];
  const float* Wq     = (const float*)d_in[9];
  const float* Wk     = (const float*)d_in[10];
  const float* Wv     = (const float*)d_in[11];
  const float* Wo     = (const float*)d_in[12];
  const float* bo     = (const float*)d_in[13];
  const float* ln1_g  = (const float*)d_in[14];
  const float* ln1_b  = (const float*)d_in[15];
  const float* Wf1    = (const float*)d_in[16];
  const float* bf1    = (const float*)d_in[17];
  const float* Wf2    = (const float*)d_in[18];
  const float* bf2    = (const float*)d_in[19];
  const float* W_pred = (const float*)d_in[20];
  const float* b_pred = (const float*)d_in[21];
  float* out = (float*)d_out;

  char* p = (char*)d_ws;
  auto alloc = [&](size_t bytes) { char* r = p; p += (bytes + 255) & ~(size_t)255; return r; };
  const size_t MB = 1024 * 1024;
  _Float16* whqkv_h = (_Float16*)alloc(6 * MB);
  _Float16* whqkv_l = (_Float16*)alloc(6 * MB);
  _Float16* who_h   = (_Float16*)alloc(2 * MB);
  _Float16* who_l   = (_Float16*)alloc(2 * MB);
  _Float16* whf1_h  = (_Float16*)alloc(8 * MB);
  _Float16* whf1_l  = (_Float16*)alloc(8 * MB);
  _Float16* whf2_h  = (_Float16*)alloc(8 * MB);
  _Float16* whf2_l  = (_Float16*)alloc(8 * MB);
  float*    e       = (float*)alloc(16 * MB);   // embed; later aliased as attn_out
  float*    x       = (float*)alloc(16 * MB);
  _Float16* xh_h    = (_Float16*)alloc(8 * MB);
  _Float16* xh_l    = (_Float16*)alloc(8 * MB);
  _Float16* av_h    = (_Float16*)alloc(8 * MB);
  _Float16* av_l    = (_Float16*)alloc(8 * MB);
  _Float16* h1_h    = (_Float16*)alloc(8 * MB);
  _Float16* h1_l    = (_Float16*)alloc(8 * MB);
  float*    Mp      = (float*)alloc(4 * MB);
  float*    pred_p  = (float*)alloc(2048 * 4);
  char*     U       = alloc(64 * MB);           // union: qkv pair | fh pair (disjoint lifetimes)
  _Float16* qkv_h = (_Float16*)U;
  _Float16* qkv_l = (_Float16*)(U + 24 * MB);
  _Float16* fh_h  = (_Float16*)U;
  _Float16* fh_l  = (_Float16*)(U + 32 * MB);
  float* ao = e;

  auto f2h = [&](const float* s, _Float16* hh, _Float16* ll, int n) {
    int blocks = (n / 4 + 255) / 256; if (blocks > 2048) blocks = 2048;
    f2h_split_kernel<<<blocks, 256, 0, stream>>>(s, hh, ll, n);
  };

  embed_kernel<<<4096, 256, 0, stream>>>(obs, act, W_obs, b_obs, W_act, b_act, e);
  ln_kernel<false, true><<<4096, 256, 0, stream>>>(e, nullptr, ln0_g, ln0_b, x, xh_h, xh_l);

  for (int l = 0; l < 6; ++l) {
    const size_t dd = (size_t)l * 1024 * 1024, df = (size_t)l * 4096 * 1024;
    f2h(Wq + dd, whqkv_h,           whqkv_l,           1048576);
    f2h(Wk + dd, whqkv_h + 1048576, whqkv_l + 1048576, 1048576);
    f2h(Wv + dd, whqkv_h + 2097152, whqkv_l + 2097152, 1048576);
    f2h(Wo + dd, who_h,  who_l,  1048576);
    f2h(Wf1 + df, whf1_h, whf1_l, 4194304);
    f2h(Wf2 + df, whf2_h, whf2_l, 4194304);

    // qkv = x @ [Wq;Wk;Wv]^T   (M=4096, N=3072, K=1024) -- 256^2 phase-split
    gemm256<false, false><<<dim3(12, 16), 512, 0, stream>>>(
        xh_h, xh_l, whqkv_h, whqkv_l, nullptr, qkv_h, qkv_l, 3072, 1024);
    // M = K^T V partials, then av = scale * Q @ M
    ktv_kernel<<<256, 256, 0, stream>>>(qkv_h, qkv_l, Mp);
    av_kernel<<<512, 256, 0, stream>>>(qkv_h, qkv_l, Mp, av_h, av_l);
    // attn_out = av @ Wo^T + bo  (N=1024 -> keep 128^2)
    gemm_bt<true, false, true, false><<<dim3(8, 32), 256, 0, stream>>>(
        av_h, av_l, who_h, who_l, bo + (size_t)l * 1024, ao, nullptr, nullptr, 4096, 1024, 1024);
    // h1 = LN(x + attn_out)
    ln_kernel<true, false><<<4096, 256, 0, stream>>>(
        x, ao, ln1_g + (size_t)l * 1024, ln1_b + (size_t)l * 1024, nullptr, h1_h, h1_l);
    // f = gelu(h1 @ Wf1^T + bf1)  (N=4096 -> 256^2 phase-split)
    gemm256<true, true><<<dim3(16, 16), 512, 0, stream>>>(
        h1_h, h1_l, whf1_h, whf1_l, bf1 + (size_t)l * 4096, fh_h, fh_l, 4096, 1024);
    // x = f @ Wf2^T + bf2  (N=1024 -> keep 128^2)
    gemm_bt<true, false, true, true><<<dim3(8, 32), 256, 0, stream>>>(
        fh_h, fh_l, whf2_h, whf2_l, bf2 + (size_t)l * 1024, x, xh_h, xh_l, 4096, 1024, 4096);
  }

  pred_split1<<<2048, 256, 0, stream>>>(x, W_pred, pred_p);
  pred_split2<<<32, 64, 0, stream>>>(pred_p, b_pred, out);
}